// Round 1
// baseline (377.850 us; speedup 1.0000x reference)
//
#include <hip/hip_runtime.h>

#define THREADS 256
#define IMG_PER_BLOCK 2

__device__ __forceinline__ float sigmoidf(float x) {
    return 1.0f / (1.0f + __expf(-x));
}

// Effective-weight gather helper.
// IG=false: wp already holds gathered weights (from ws). IG=true: gather inline.
template<bool IG>
__device__ __forceinline__ float wget(const float* __restrict__ wp,
                                      const float* __restrict__ sg,
                                      const int* __restrict__ sr,
                                      int row, int m, int idx, bool tg) {
    if (!IG) {
        return wp[row * m + idx];
    } else {
        int f = row * m + idx;
        return tg ? sg[f] * wp[row * m + sr[f]] : wp[f];
    }
}

// Precompute effective weights into ws: e1 at [0,150) (padded to 160),
// e2 at [160, 2560), e3 at [2560, 50560).
__global__ void weff_prep(const float* __restrict__ w1, const float* __restrict__ sg1, const int* __restrict__ sr1,
                          const float* __restrict__ w2, const float* __restrict__ sg2, const int* __restrict__ sr2,
                          const float* __restrict__ w3, const float* __restrict__ sg3, const int* __restrict__ sr3,
                          const int* __restrict__ trig, float* __restrict__ ws) {
    int i = blockIdx.x * blockDim.x + threadIdx.x;
    const int t = trig[0];
    float* e1 = ws;
    float* e2 = ws + 160;
    float* e3 = ws + 2560;
    if (i < 150) {
        int r = i / 25;
        e1[i] = t ? sg1[i] * w1[r * 25 + sr1[i]] : w1[i];
    } else if (i < 2550) {
        int k = i - 150;
        int r = k / 150;
        e2[k] = t ? sg2[k] * w2[r * 150 + sr2[k]] : w2[k];
    } else if (i < 50550) {
        int k = i - 2550;
        int r = k / 400;
        e3[k] = t ? sg3[k] * w3[r * 400 + sr3[k]] : w3[k];
    }
}

template<bool IG>
__global__ __launch_bounds__(THREADS, 4)
void lenet_fused(const float* __restrict__ x,
                 const float* __restrict__ w1e, const float* __restrict__ b1,
                 const float* __restrict__ w2e, const float* __restrict__ b2,
                 const float* __restrict__ w3e, const float* __restrict__ b3,
                 const float* __restrict__ fc1w, const float* __restrict__ fc1b,
                 const float* __restrict__ fc2w, const float* __restrict__ fc2b,
                 const float* __restrict__ sg1, const int* __restrict__ sr1,
                 const float* __restrict__ sg2, const int* __restrict__ sr2,
                 const float* __restrict__ sg3, const int* __restrict__ sr3,
                 const int* __restrict__ trig,
                 float* __restrict__ out, int nimg) {
    const int tid = threadIdx.x;
    const int img0 = blockIdx.x * IMG_PER_BLOCK;

    __shared__ __align__(16) float xs[IMG_PER_BLOCK][1024];
    __shared__ __align__(16) float p1[IMG_PER_BLOCK][6][196];
    __shared__ __align__(16) float p2[IMG_PER_BLOCK][400];
    __shared__ __align__(16) float v3[IMG_PER_BLOCK][120];
    __shared__ __align__(16) float v4[IMG_PER_BLOCK][84];

    const bool tg = IG ? (trig[0] != 0) : false;

    // ---- stage 0: stage input images into LDS (coalesced float4) ----
    #pragma unroll
    for (int im = 0; im < IMG_PER_BLOCK; ++im) {
        int gi = min(img0 + im, nimg - 1);
        const float4* src = reinterpret_cast<const float4*>(x + (size_t)gi * 1024);
        float4* dst = reinterpret_cast<float4*>(&xs[im][0]);
        dst[tid] = src[tid];  // 1024/4 = 256 float4 per image, 256 threads
    }
    __syncthreads();

    // ---- stage 1: conv1(5x5, 1->6) + sigmoid + avgpool2, fused ----
    // thread item = (img, pooled pixel). 6x6 patch in regs, reused for all 6
    // out-channels and all 4 pool windows. Weights: wave-uniform -> s_load.
    for (int it = tid; it < IMG_PER_BLOCK * 196; it += THREADS) {
        const int img = it / 196;
        const int pix = it % 196;
        const int pi = pix / 14;
        const int pj = pix % 14;
        const float* xb = &xs[img][(2 * pi) * 32 + 2 * pj];
        float pt[6][6];
        #pragma unroll
        for (int r = 0; r < 6; ++r) {
            #pragma unroll
            for (int cc = 0; cc < 3; ++cc) {
                float2 v = *reinterpret_cast<const float2*>(&xb[r * 32 + cc * 2]);
                pt[r][cc * 2] = v.x;
                pt[r][cc * 2 + 1] = v.y;
            }
        }
        #pragma unroll
        for (int c = 0; c < 6; ++c) {
            float z00 = 0.f, z01 = 0.f, z10 = 0.f, z11 = 0.f;
            #pragma unroll
            for (int ky = 0; ky < 5; ++ky) {
                #pragma unroll
                for (int kx = 0; kx < 5; ++kx) {
                    const float wv = wget<IG>(w1e, sg1, sr1, c, 25, ky * 5 + kx, tg);
                    z00 += pt[ky][kx] * wv;
                    z01 += pt[ky][kx + 1] * wv;
                    z10 += pt[ky + 1][kx] * wv;
                    z11 += pt[ky + 1][kx + 1] * wv;
                }
            }
            const float bb = b1[c];
            float s = sigmoidf(z00 + bb) + sigmoidf(z01 + bb) +
                      sigmoidf(z10 + bb) + sigmoidf(z11 + bb);
            p1[img][c][pix] = 0.25f * s;
        }
    }
    __syncthreads();

    // ---- stage 2: conv2(5x5, 6->16) + sigmoid + avgpool2, fused ----
    // thread item = (img, pooled pixel, pool window). acc over all 16 out-ch.
    // Weights wave-uniform -> SGPR. Pool-combine via shfl_xor over 4 lanes.
    if (tid < IMG_PER_BLOCK * 100) {
        const int img = tid / 100;
        const int rem = tid % 100;
        const int pix = rem >> 2;   // 0..24
        const int win = rem & 3;
        const int di = win >> 1, dj = win & 1;
        const int pi = pix / 5, pj = pix % 5;
        const int r0 = 2 * pi + di, c0 = 2 * pj + dj;
        float acc[16];
        #pragma unroll
        for (int c = 0; c < 16; ++c) acc[c] = 0.f;
        for (int ic = 0; ic < 6; ++ic) {
            float pt[5][5];
            #pragma unroll
            for (int ky = 0; ky < 5; ++ky)
                #pragma unroll
                for (int kx = 0; kx < 5; ++kx)
                    pt[ky][kx] = p1[img][ic][(r0 + ky) * 14 + (c0 + kx)];
            #pragma unroll
            for (int c = 0; c < 16; ++c) {
                float z = acc[c];
                #pragma unroll
                for (int ky = 0; ky < 5; ++ky)
                    #pragma unroll
                    for (int kx = 0; kx < 5; ++kx)
                        z += pt[ky][kx] * wget<IG>(w2e, sg2, sr2, c, 150, ic * 25 + ky * 5 + kx, tg);
                acc[c] = z;
            }
        }
        #pragma unroll
        for (int c = 0; c < 16; ++c) {
            float z = sigmoidf(acc[c] + b2[c]);
            z += __shfl_xor(z, 1, 64);
            z += __shfl_xor(z, 2, 64);
            if (win == 0) p2[img][c * 25 + pix] = 0.25f * z;
        }
    }
    __syncthreads();

    // ---- stage 3: conv3 (5x5, 16->120, output 1x1) + sigmoid ----
    // thread = (out-channel c, K-half h). Weight float4 loaded once, used for
    // BOTH images (halves L2 weight traffic). Pair-reduce via shfl_xor.
    if (tid < 240) {
        const int c = tid >> 1;
        const int h = tid & 1;
        float z0, z1;
        if (!IG) {
            const float4* wp = reinterpret_cast<const float4*>(w3e + c * 400 + h * 200);
            const float4* q0 = reinterpret_cast<const float4*>(&p2[0][h * 200]);
            const float4* q1 = reinterpret_cast<const float4*>(&p2[1][h * 200]);
            float4 a0 = {0.f, 0.f, 0.f, 0.f}, a1 = {0.f, 0.f, 0.f, 0.f};
            #pragma unroll 5
            for (int k = 0; k < 50; ++k) {
                float4 w4 = wp[k];
                float4 u0 = q0[k];
                float4 u1 = q1[k];
                a0.x += u0.x * w4.x; a0.y += u0.y * w4.y;
                a0.z += u0.z * w4.z; a0.w += u0.w * w4.w;
                a1.x += u1.x * w4.x; a1.y += u1.y * w4.y;
                a1.z += u1.z * w4.z; a1.w += u1.w * w4.w;
            }
            z0 = (a0.x + a0.y) + (a0.z + a0.w);
            z1 = (a1.x + a1.y) + (a1.z + a1.w);
        } else {
            float s0 = 0.f, s1 = 0.f;
            for (int k = 0; k < 200; ++k) {
                float wv = wget<true>(w3e, sg3, sr3, c, 400, h * 200 + k, tg);
                s0 += p2[0][h * 200 + k] * wv;
                s1 += p2[1][h * 200 + k] * wv;
            }
            z0 = s0; z1 = s1;
        }
        z0 += __shfl_xor(z0, 1, 64);
        z1 += __shfl_xor(z1, 1, 64);
        if (h == 0) {
            const float bb = b3[c];
            v3[0][c] = sigmoidf(z0 + bb);
            v3[1][c] = sigmoidf(z1 + bb);
        }
    }
    __syncthreads();

    // ---- stage 4: fc1 (120 -> 84) + sigmoid ----
    if (tid < IMG_PER_BLOCK * 84) {
        const int img = tid / 84;
        const int j = tid % 84;
        const float4* wp = reinterpret_cast<const float4*>(fc1w + j * 120);
        const float4* vp = reinterpret_cast<const float4*>(&v3[img][0]);
        float4 a = {0.f, 0.f, 0.f, 0.f};
        #pragma unroll 6
        for (int k = 0; k < 30; ++k) {
            float4 w4 = wp[k];
            float4 u = vp[k];
            a.x += u.x * w4.x; a.y += u.y * w4.y;
            a.z += u.z * w4.z; a.w += u.w * w4.w;
        }
        v4[img][j] = sigmoidf((a.x + a.y) + (a.z + a.w) + fc1b[j]);
    }
    __syncthreads();

    // ---- stage 5: fc2 (84 -> 10) ----
    if (tid < IMG_PER_BLOCK * 10) {
        const int img = tid / 10;
        const int j = tid % 10;
        if (img0 + img < nimg) {
            const float* wp = fc2w + j * 84;
            const float* vp = &v4[img][0];
            float a = 0.f, b = 0.f, c2 = 0.f, d = 0.f;
            #pragma unroll
            for (int k = 0; k < 84; k += 4) {
                a  += vp[k]     * wp[k];
                b  += vp[k + 1] * wp[k + 1];
                c2 += vp[k + 2] * wp[k + 2];
                d  += vp[k + 3] * wp[k + 3];
            }
            out[(size_t)(img0 + img) * 10 + j] = (a + b) + (c2 + d) + fc2b[j];
        }
    }
}

extern "C" void kernel_launch(void* const* d_in, const int* in_sizes, int n_in,
                              void* d_out, int out_size, void* d_ws, size_t ws_size,
                              hipStream_t stream) {
    const float* x    = (const float*)d_in[0];
    const float* w1   = (const float*)d_in[1];
    const float* b1   = (const float*)d_in[2];
    const float* sg1  = (const float*)d_in[3];
    const float* w2   = (const float*)d_in[4];
    const float* b2   = (const float*)d_in[5];
    const float* sg2  = (const float*)d_in[6];
    const float* w3   = (const float*)d_in[7];
    const float* b3   = (const float*)d_in[8];
    const float* sg3  = (const float*)d_in[9];
    const float* fc1w = (const float*)d_in[10];
    const float* fc1b = (const float*)d_in[11];
    const float* fc2w = (const float*)d_in[12];
    const float* fc2b = (const float*)d_in[13];
    const int*   sr1  = (const int*)d_in[14];
    const int*   sr2  = (const int*)d_in[15];
    const int*   sr3  = (const int*)d_in[16];
    const int*   trig = (const int*)d_in[17];

    const int nimg = in_sizes[0] / 1024;
    const int nblk = (nimg + IMG_PER_BLOCK - 1) / IMG_PER_BLOCK;
    float* out = (float*)d_out;

    const size_t WEFF_BYTES = (size_t)(160 + 2400 + 48000) * sizeof(float);
    if (ws_size >= WEFF_BYTES) {
        float* ws = (float*)d_ws;
        weff_prep<<<(50550 + 255) / 256, 256, 0, stream>>>(
            w1, sg1, sr1, w2, sg2, sr2, w3, sg3, sr3, trig, ws);
        lenet_fused<false><<<nblk, THREADS, 0, stream>>>(
            x, ws, b1, ws + 160, b2, ws + 2560, b3,
            fc1w, fc1b, fc2w, fc2b, sg1, sr1, sg2, sr2, sg3, sr3, trig, out, nimg);
    } else {
        lenet_fused<true><<<nblk, THREADS, 0, stream>>>(
            x, w1, b1, w2, b2, w3, b3,
            fc1w, fc1b, fc2w, fc2b, sg1, sr1, sg2, sr2, sg3, sr3, trig, out, nimg);
    }
}